// Round 6
// baseline (627.898 us; speedup 1.0000x reference)
//
#include <hip/hip_runtime.h>
#include <math.h>

typedef float float4u __attribute__((ext_vector_type(4), aligned(4)));

// ---------------------------------------------------------------------------
// VQCodebook forward, MI355X. B=256, D=128, K=8192, fp32.  3 kernels:
//  K1 conv1+ReLU+stats: 4096 blocks (batch x 4 stripes x 4 colblocks),
//     column-strip rolling-window conv; compact stats; atomic last-block
//     winner computes S -> z -> ||z||^2.  + prework Wcfg/||e||^2 (320 blocks)
//  K2 VQ partial argmin (512 blocks: 32 bgroups x 16 kc)
//  K3 argmin + losses + indices + decoder stage-1/2/3 + expand (256 blocks)
// ---------------------------------------------------------------------------

// ------------------ K1 ------------------
__global__ __launch_bounds__(256) void k_conv_z(
    const float* __restrict__ patch, const float* __restrict__ w1,
    const float* __restrict__ b1, const float* __restrict__ w2,
    const float* __restrict__ b2, const float* __restrict__ dw1,
    const float* __restrict__ emb,
    float* __restrict__ pstat, int* __restrict__ cnt,
    float* __restrict__ z, float* __restrict__ zn2,
    float* __restrict__ Wcfg, float* __restrict__ en2)
{
    __shared__ __align__(16) float lds[2304];
    __shared__ int winflag;
    const int blk = blockIdx.x, tid = threadIdx.x;

    if (blk >= 4096) {   // ---- prework ----
        const int gid = (blk - 4096) * 256 + tid;
        if (gid < 73728) {
            const int cfg = gid >> 13;
            const int o = (gid >> 7) & 63;
            const int i = gid & 127;
            const int cy = cfg / 3, cx = cfg % 3;
            const int ylo = (cy == 2) ? 1 : 0, yhi = (cy == 0) ? 1 : 2;
            const int xlo = (cx == 2) ? 1 : 0, xhi = (cx == 0) ? 1 : 2;
            const float* wp = dw1 + ((size_t)i * 64 + o) * 9;
            float s = 0.f;
            for (int ky = ylo; ky <= yhi; ++ky)
                for (int kx = xlo; kx <= xhi; ++kx)
                    s += wp[ky * 3 + kx];
            Wcfg[gid] = s;
        } else if (gid < 81920) {
            const int k = gid - 73728;
            const float4* e = (const float4*)(emb + (size_t)k * 128);
            float s = 0.f;
            for (int t = 0; t < 32; ++t) {
                const float4 v = e[t];
                s = fmaf(v.x, v.x, fmaf(v.y, v.y, fmaf(v.z, v.z, fmaf(v.w, v.w, s))));
            }
            en2[k] = s;
        }
        return;
    }

    // ---- conv block: batch b, rows stripe*16.., cols colblk*16.. ----
    const int b = blk >> 4, stripe = (blk >> 2) & 3, colblk = blk & 3;
    const float* pb = patch + (size_t)b * 12288;

    // stage [ic:3][r:18][p:20]; r holds y=stripe*16+r-1, p holds x=colblk*16+p-1
    for (int i = tid; i < 1080; i += 256) {
        const int ic = i / 360, rem = i - ic * 360;
        const int r = rem / 20, p = rem - r * 20;
        const int y = stripe * 16 + r - 1, x = colblk * 16 + p - 1;
        float v = 0.f;
        if (y >= 0 && y < 64 && x >= 0 && x < 64)
            v = pb[(ic << 12) + (y << 6) + x];
        lds[i] = v;
    }
    __syncthreads();

    const int ch = tid & 63, cg = tid >> 6;   // 4 cols per thread
    float wgt[3][3][3];
#pragma unroll
    for (int ic = 0; ic < 3; ++ic)
#pragma unroll
        for (int ky = 0; ky < 3; ++ky)
#pragma unroll
            for (int kx = 0; kx < 3; ++kx)
                wgt[ic][ky][kx] = w1[((ch * 3 + ic) * 3 + ky) * 3 + kx];
    const float bias = b1[ch];

    const float* base = lds + cg * 4;   // loop-invariant; all reads offset:imm
    const bool atC0  = (cg == 0) && (colblk == 0);
    const bool atC63 = (cg == 3) && (colblk == 3);

    float win[3][3][6];
#pragma unroll
    for (int ic = 0; ic < 3; ++ic)
#pragma unroll
        for (int rr = 0; rr < 2; ++rr) {
            const float4 f4 = *(const float4*)(base + (ic * 18 + rr) * 20);
            const float2 f2 = *(const float2*)(base + (ic * 18 + rr) * 20 + 4);
            win[ic][rr][0] = f4.x; win[ic][rr][1] = f4.y; win[ic][rr][2] = f4.z;
            win[ic][rr][3] = f4.w; win[ic][rr][4] = f2.x; win[ic][rr][5] = f2.y;
        }

    float T = 0, r0s = 0, r63s = 0, c0s = 0, c63s = 0;
    float h00 = 0, h063 = 0, h630 = 0, h6363 = 0;

#pragma unroll
    for (int y = 0; y < 16; ++y) {
        const int s2 = (y + 2) % 3;
#pragma unroll
        for (int ic = 0; ic < 3; ++ic) {
            const float4 f4 = *(const float4*)(base + (ic * 18 + y + 2) * 20);
            const float2 f2 = *(const float2*)(base + (ic * 18 + y + 2) * 20 + 4);
            win[ic][s2][0] = f4.x; win[ic][s2][1] = f4.y; win[ic][s2][2] = f4.z;
            win[ic][s2][3] = f4.w; win[ic][s2][4] = f2.x; win[ic][s2][5] = f2.y;
        }
        float a0 = bias, a1 = bias, a2 = bias, a3 = bias;
#pragma unroll
        for (int ic = 0; ic < 3; ++ic)
#pragma unroll
            for (int k = 0; k < 3; ++k) {
                const int sl = (y + k) % 3;
                const float f0 = win[ic][sl][0], f1 = win[ic][sl][1], f2v = win[ic][sl][2];
                const float f3 = win[ic][sl][3], f4v = win[ic][sl][4], f5 = win[ic][sl][5];
                const float wa = wgt[ic][k][0], wb = wgt[ic][k][1], wc = wgt[ic][k][2];
                a0 = fmaf(wa, f0, fmaf(wb, f1, fmaf(wc, f2v, a0)));
                a1 = fmaf(wa, f1, fmaf(wb, f2v, fmaf(wc, f3, a1)));
                a2 = fmaf(wa, f2v, fmaf(wb, f3, fmaf(wc, f4v, a2)));
                a3 = fmaf(wa, f3, fmaf(wb, f4v, fmaf(wc, f5, a3)));
            }
        a0 = fmaxf(a0, 0.f); a1 = fmaxf(a1, 0.f);
        a2 = fmaxf(a2, 0.f); a3 = fmaxf(a3, 0.f);
        const float rs = (a0 + a1) + (a2 + a3);
        T += rs;
        if (atC0)  c0s  += a0;
        if (atC63) c63s += a3;
        if (stripe == 0 && y == 0) {
            r0s = rs;
            if (atC0)  h00  = a0;
            if (atC63) h063 = a3;
        }
        if (stripe == 3 && y == 15) {
            r63s = rs;
            if (atC0)  h630 = a0;
            if (atC63) h6363 = a3;
        }
    }
    __syncthreads();   // conv reads done; reuse LDS

    {
        const float st[9] = {T, r0s, r63s, c0s, c63s, h00, h063, h630, h6363};
#pragma unroll
        for (int s = 0; s < 9; ++s) lds[(s * 4 + cg) * 64 + ch] = st[s];
    }
    __syncthreads();

    if (tid < 64) {
        float f[9];
#pragma unroll
        for (int s = 0; s < 9; ++s)
            f[s] = (lds[(s * 4 + 0) * 64 + tid] + lds[(s * 4 + 1) * 64 + tid])
                 + (lds[(s * 4 + 2) * 64 + tid] + lds[(s * 4 + 3) * 64 + tid]);
        float* pp = pstat + (size_t)b * 2304;
        const int blk16 = stripe * 4 + colblk;
        pp[blk16 * 64 + tid] = f[0];                              // T partial
        if (stripe == 0) pp[1024 + colblk * 64 + tid] = f[1];     // r0
        if (stripe == 3) pp[1280 + colblk * 64 + tid] = f[2];     // r63
        if (colblk == 0) pp[1536 + stripe * 64 + tid] = f[3];     // c0
        if (colblk == 3) pp[1792 + stripe * 64 + tid] = f[4];     // c63
        if (stripe == 0 && colblk == 0) pp[2048 + tid] = f[5];    // h00
        if (stripe == 0 && colblk == 3) pp[2112 + tid] = f[6];    // h063
        if (stripe == 3 && colblk == 0) pp[2176 + tid] = f[7];    // h630
        if (stripe == 3 && colblk == 3) pp[2240 + tid] = f[8];    // h6363
    }
    __threadfence();
    __syncthreads();
    if (tid == 0) winflag = (atomicAdd(&cnt[b], 1) == 15) ? 1 : 0;
    __syncthreads();
    if (!winflag) return;
    __threadfence();   // acquire other blocks' pstat writes

    // ---- winner: stats -> S -> z -> ||z||^2 ----
    float* Ssh  = lds;          // 576
    float* zp   = lds + 576;    // 256
    float* red2 = lds + 832;    // 128
    const volatile float* vp = pstat + (size_t)b * 2304;
    if (tid < 64) {
        float Tt = 0.f;
#pragma unroll
        for (int g = 0; g < 16; ++g) Tt += vp[g * 64 + tid];
        float R0 = 0.f, R63 = 0.f, C0 = 0.f, C63 = 0.f;
#pragma unroll
        for (int c = 0; c < 4; ++c) {
            R0  += vp[1024 + c * 64 + tid];
            R63 += vp[1280 + c * 64 + tid];
            C0  += vp[1536 + c * 64 + tid];
            C63 += vp[1792 + c * 64 + tid];
        }
        const float H00 = vp[2048 + tid], H063 = vp[2112 + tid];
        const float H630 = vp[2176 + tid], H6363 = vp[2240 + tid];
#pragma unroll
        for (int ky = 0; ky < 3; ++ky) {
            const float rex = (ky == 0) ? R63 : (ky == 2 ? R0 : 0.f);
#pragma unroll
            for (int kx = 0; kx < 3; ++kx) {
                const float cex = (kx == 0) ? C63 : (kx == 2 ? C0 : 0.f);
                float corner = 0.f;
                if (ky == 0 && kx == 0) corner = H6363;
                if (ky == 0 && kx == 2) corner = H630;
                if (ky == 2 && kx == 0) corner = H063;
                if (ky == 2 && kx == 2) corner = H00;
                Ssh[tid * 9 + ky * 3 + kx] = (Tt - rex - cex + corner) * (1.f / 4096.f);
            }
        }
    }
    __syncthreads();
    {
        const int oc = tid & 127, h = tid >> 7;
        const float4* Wv = (const float4*)(w2 + (size_t)oc * 576 + h * 288);
        const float4* Sv = (const float4*)(Ssh + h * 288);
        float acc = 0.f;
        for (int t = 0; t < 72; ++t) {
            const float4 w4 = Wv[t], s4 = Sv[t];
            acc = fmaf(w4.x, s4.x, acc);
            acc = fmaf(w4.y, s4.y, acc);
            acc = fmaf(w4.z, s4.z, acc);
            acc = fmaf(w4.w, s4.w, acc);
        }
        zp[tid] = acc;
    }
    __syncthreads();
    if (tid < 128) {
        const float zv = b2[tid] + zp[tid] + zp[tid + 128];
        z[(size_t)b * 128 + tid] = zv;
        red2[tid] = zv * zv;
    }
    __syncthreads();
    if (tid < 64) {
        float v = red2[tid] + red2[tid + 64];
        v += __shfl_xor(v, 32); v += __shfl_xor(v, 16); v += __shfl_xor(v, 8);
        v += __shfl_xor(v, 4);  v += __shfl_xor(v, 2);  v += __shfl_xor(v, 1);
        if (tid == 0) zn2[b] = v;
    }
}

// ------------------ K2: VQ partial argmin (32 bg x 16 kc) ------------------
__global__ __launch_bounds__(256) void k_vq(
    const float* __restrict__ z, const float* __restrict__ emb,
    const float* __restrict__ en2, float* __restrict__ pd2, int* __restrict__ pidx)
{
    __shared__ __align__(16) float zsh[1024];
    __shared__ float wd[8][4];
    __shared__ int   wi[8][4];
    const int tid = threadIdx.x;
    const int bg = blockIdx.x >> 4, kc = blockIdx.x & 15;
    const int b0 = bg * 8;
    for (int i = tid; i < 1024; i += 256) zsh[i] = z[(size_t)b0 * 128 + i];
    __syncthreads();

    const int k0 = kc * 512 + tid, k1 = k0 + 256;
    const float4* e0 = (const float4*)(emb + (size_t)k0 * 128);
    const float4* e1 = (const float4*)(emb + (size_t)k1 * 128);
    const float4* zv = (const float4*)zsh;

    float acc0[8], acc1[8];
#pragma unroll
    for (int bb = 0; bb < 8; ++bb) { acc0[bb] = 0.f; acc1[bb] = 0.f; }

    for (int t = 0; t < 32; ++t) {
        const float4 ea = e0[t], eb = e1[t];
#pragma unroll
        for (int bb = 0; bb < 8; ++bb) {
            const float4 zz = zv[bb * 32 + t];
            acc0[bb] = fmaf(zz.x, ea.x, fmaf(zz.y, ea.y, fmaf(zz.z, ea.z, fmaf(zz.w, ea.w, acc0[bb]))));
            acc1[bb] = fmaf(zz.x, eb.x, fmaf(zz.y, eb.y, fmaf(zz.z, eb.z, fmaf(zz.w, eb.w, acc1[bb]))));
        }
    }
    const float E0 = en2[k0], E1 = en2[k1];
    const int wv_ = tid >> 6, ln = tid & 63;
#pragma unroll
    for (int bb = 0; bb < 8; ++bb) {
        const float da = fmaf(-2.f, acc0[bb], E0);
        const float db = fmaf(-2.f, acc1[bb], E1);
        float d; int ix;
        if (da <= db) { d = da; ix = k0; } else { d = db; ix = k1; }
#pragma unroll
        for (int off = 32; off > 0; off >>= 1) {
            const float od = __shfl_xor(d, off);
            const int   oi = __shfl_xor(ix, off);
            if (od < d || (od == d && oi < ix)) { d = od; ix = oi; }
        }
        if (ln == 0) { wd[bb][wv_] = d; wi[bb][wv_] = ix; }
    }
    __syncthreads();
    if (tid < 8) {
        float d = wd[tid][0]; int ix = wi[tid][0];
#pragma unroll
        for (int wv2 = 1; wv2 < 4; ++wv2) {
            const float od = wd[tid][wv2]; const int oi = wi[tid][wv2];
            if (od < d || (od == d && oi < ix)) { d = od; ix = oi; }
        }
        pd2[(b0 + tid) * 16 + kc] = d;
        pidx[(b0 + tid) * 16 + kc] = ix;
    }
}

// ------------------ K3: argmin + losses + indices + full decoder + expand ------------------
__global__ __launch_bounds__(256) void k_decode(
    const float* __restrict__ emb, const float* __restrict__ zn2,
    const float* __restrict__ pd2, const int* __restrict__ pidx,
    const float* __restrict__ Wcfg, const float* __restrict__ db1,
    const float* __restrict__ dw2, const float* __restrict__ db2,
    const float* __restrict__ dw3, const float* __restrict__ db3,
    float* __restrict__ out)
{
    __shared__ __align__(16) float zsh[128];
    __shared__ float d1e[64][10];
    __shared__ float d2e[64][26];
    __shared__ float o3[3 * 49];
    __shared__ float dw3sh[1728];
    __shared__ float redl[256];
    __shared__ int bsel;

    const int b = blockIdx.x, tid = threadIdx.x;

    // ---- phase 0: final argmin, batch 'tid' per thread ----
    float dmin = pd2[tid * 16]; int bi = pidx[tid * 16];
    for (int j = 1; j < 16; ++j) {
        const float d = pd2[tid * 16 + j]; const int ix = pidx[tid * 16 + j];
        if (d < dmin || (d == dmin && ix < bi)) { dmin = d; bi = ix; }
    }
    if (tid == b) bsel = bi;
    redl[tid] = dmin + zn2[tid];
    __syncthreads();

    if (b == 0) out[3145730 + tid] = (float)bi;
    if (tid < 128) {
        redl[tid] += redl[tid + 128];
        zsh[tid] = emb[(size_t)bsel * 128 + tid];
    }
    for (int id = tid; id < 1728; id += 256) dw3sh[id] = dw3[id];
    if (tid < 64) { d1e[tid][9] = 0.f; d2e[tid][25] = 0.f; }
    __syncthreads();

    if (tid < 64) {
        float v = redl[tid] + redl[tid + 64];
        v += __shfl_xor(v, 32); v += __shfl_xor(v, 16); v += __shfl_xor(v, 8);
        v += __shfl_xor(v, 4);  v += __shfl_xor(v, 2);  v += __shfl_xor(v, 1);
        if (tid == 0 && b == 0) {
            const float L = v * (1.f / 32768.f);
            out[3145728] = L;
            out[3145729] = L;
        }
    }

    // ---- stage 1: d1e[o][cfg] = relu(db1 + Wcfg[cfg][o][:] . zq) ----
    for (int id = tid; id < 576; id += 256) {
        const int o = id / 9, cfg = id - o * 9;
        const float4* wv = (const float4*)(Wcfg + ((size_t)cfg * 64 + o) * 128);
        const float4* zv = (const float4*)zsh;
        float acc = db1[o];
        for (int t = 0; t < 32; ++t) {
            const float4 w4 = wv[t], z4 = zv[t];
            acc = fmaf(w4.x, z4.x, acc);
            acc = fmaf(w4.y, z4.y, acc);
            acc = fmaf(w4.z, z4.z, acc);
            acc = fmaf(w4.w, z4.w, acc);
        }
        d1e[o][cfg] = fmaxf(acc, 0.f);
    }
    __syncthreads();

    // ---- stage 2: 25 cfgs; thread = (o, i-quarter); shfl reduce ----
    {
        const int TY5[5][3] = {{-1,0,1},{0,1,1},{1,1,1},{1,1,2},{1,2,-1}};
        const int o = tid >> 2, isub = tid & 3;
        float acc[25];
#pragma unroll
        for (int cc = 0; cc < 25; ++cc) acc[cc] = 0.f;
        for (int ii = 0; ii < 16; ++ii) {
            const int i = isub + ii * 4;
            float d1v[10];
#pragma unroll
            for (int t = 0; t < 9; ++t) d1v[t] = d1e[i][t];
            d1v[9] = 0.f;
            const float* wp = dw2 + ((size_t)i * 64 + o) * 9;
            const float4u w03 = *(const float4u*)wp;
            const float4u w47 = *(const float4u*)(wp + 4);
            const float w8v = wp[8];
            const float w9[9] = {w03.x, w03.y, w03.z, w03.w, w47.x, w47.y, w47.z, w47.w, w8v};
#pragma unroll
            for (int cy = 0; cy < 5; ++cy) {
#pragma unroll
                for (int ky = 0; ky < 3; ++ky) {
                    const int ty = TY5[cy][ky];
                    if (ty < 0) continue;
#pragma unroll
                    for (int cx = 0; cx < 5; ++cx) {
#pragma unroll
                        for (int kx = 0; kx < 3; ++kx) {
                            const int tx = TY5[cx][kx];
                            if (tx < 0) continue;
                            acc[cy * 5 + cx] = fmaf(w9[(2 - ky) * 3 + (2 - kx)],
                                                    d1v[ty * 3 + tx], acc[cy * 5 + cx]);
                        }
                    }
                }
            }
        }
#pragma unroll
        for (int cc = 0; cc < 25; ++cc) {
            float v = acc[cc];
            v += __shfl_xor(v, 1);
            v += __shfl_xor(v, 2);
            if (isub == 0) d2e[o][cc] = fmaxf(v + db2[o], 0.f);
        }
    }
    __syncthreads();

    // ---- stage 3: 49 cfgs x 3 channels ----
    if (tid < 147) {
        const int TY7[7][3] = {{-1,0,1},{0,1,2},{1,2,2},{2,2,2},{2,2,3},{2,3,4},{3,4,-1}};
        const int c3 = tid / 49, cc = tid % 49, cy = cc / 7, cx = cc % 7;
        float acc = db3[c3];
        for (int i = 0; i < 64; ++i) {
            const float* wp = &dw3sh[(i * 3 + c3) * 9];
#pragma unroll
            for (int ky = 0; ky < 3; ++ky) {
                const int ty = TY7[cy][ky];
#pragma unroll
                for (int kx = 0; kx < 3; ++kx) {
                    const int tx = TY7[cx][kx];
                    const int t = (ty < 0 || tx < 0) ? 25 : ty * 5 + tx;
                    acc = fmaf(wp[(2 - ky) * 3 + (2 - kx)], d2e[i][t], acc);
                }
            }
        }
        o3[c3 * 49 + cc] = tanhf(acc);
    }
    __syncthreads();

    // ---- expand + float4 write ----
    float4* ob = (float4*)(out + (size_t)b * 12288);
    for (int id = tid; id < 3072; id += 256) {
        const int base = id * 4;
        const int c = base >> 12, rem = base & 4095, y = rem >> 6, x0 = rem & 63;
        const int ry = (y <= 3) ? y : (y >= 60 ? y - 57 : 3);
        const float* row = &o3[c * 49 + ry * 7];
        float4 v;
        int x;
        x = x0 + 0; v.x = row[(x <= 3) ? x : (x >= 60 ? x - 57 : 3)];
        x = x0 + 1; v.y = row[(x <= 3) ? x : (x >= 60 ? x - 57 : 3)];
        x = x0 + 2; v.z = row[(x <= 3) ? x : (x >= 60 ? x - 57 : 3)];
        x = x0 + 3; v.w = row[(x <= 3) ? x : (x >= 60 ? x - 57 : 3)];
        ob[id] = v;
    }
}

// ---------------------------------------------------------------------------
extern "C" void kernel_launch(void* const* d_in, const int* in_sizes, int n_in,
                              void* d_out, int out_size, void* d_ws, size_t ws_size,
                              hipStream_t stream)
{
    const float* patch  = (const float*)d_in[0];
    const float* enc_w1 = (const float*)d_in[1];
    const float* enc_b1 = (const float*)d_in[2];
    const float* enc_w2 = (const float*)d_in[3];
    const float* enc_b2 = (const float*)d_in[4];
    const float* emb    = (const float*)d_in[5];
    const float* dec_w1 = (const float*)d_in[6];
    const float* dec_b1 = (const float*)d_in[7];
    const float* dec_w2 = (const float*)d_in[8];
    const float* dec_b2 = (const float*)d_in[9];
    const float* dec_w3 = (const float*)d_in[10];
    const float* dec_b3 = (const float*)d_in[11];

    float* out = (float*)d_out;
    float* ws  = (float*)d_ws;

    float* pstat = ws;                     // 256*2304 = 589824
    float* z     = ws + 589824;            // 32768
    float* zn2   = ws + 622592;            // 256
    float* pd2   = ws + 622848;            // 4096
    int*   pidx  = (int*)(ws + 626944);    // 4096
    float* Wcfg  = ws + 631040;            // 73728
    float* en2   = ws + 704768;            // 8192
    int*   cnt   = (int*)(ws + 712960);    // 256 ints  (total ~2.86 MB)

    hipMemsetAsync(cnt, 0, 256 * sizeof(int), stream);

    k_conv_z<<<dim3(4416), dim3(256), 0, stream>>>(patch, enc_w1, enc_b1, enc_w2, enc_b2,
                                                   dec_w1, emb, pstat, cnt, z, zn2, Wcfg, en2);
    k_vq<<<dim3(512), dim3(256), 0, stream>>>(z, emb, en2, pd2, pidx);
    k_decode<<<dim3(256), dim3(256), 0, stream>>>(emb, zn2, pd2, pidx, Wcfg, dec_b1,
                                                  dec_w2, dec_b2, dec_w3, dec_b3, out);
}

// Round 7
// 134.293 us; speedup vs baseline: 4.6756x; 4.6756x over previous
//
#include <hip/hip_runtime.h>
#include <math.h>

typedef float float4u __attribute__((ext_vector_type(4), aligned(4)));

// ---------------------------------------------------------------------------
// VQCodebook forward, MI355X. B=256, D=128, K=8192, fp32.  4 kernels:
//  K1 conv1+ReLU+window-stats (2048 blocks, round-3 proven) + prework (320)
//  K2 stats reduce -> S -> z GEMM + ||z||^2   (256 blocks)
//  K3 VQ partial argmin (512 blocks: 32 bg x 16 kc)
//  K4 argmin + losses + indices + decoder + expand (256 blocks)
// ---------------------------------------------------------------------------

// ------------------ K1: conv1 + relu + partial stats, and pre-work ------------------
__global__ __launch_bounds__(256) void k_conv1_pre(
    const float* __restrict__ patch, const float* __restrict__ w1,
    const float* __restrict__ b1, const float* __restrict__ dw1,
    const float* __restrict__ emb, float* __restrict__ pstat,
    float* __restrict__ Wcfg, float* __restrict__ en2)
{
    __shared__ __align__(16) float lds[2304];
    const int blk = blockIdx.x;
    const int tid = threadIdx.x;

    if (blk >= 2048) {   // ---- pre-work blocks ----
        const int gid = (blk - 2048) * 256 + tid;
        if (gid < 73728) {
            const int cfg = gid >> 13;
            const int o = (gid >> 7) & 63;
            const int i = gid & 127;
            const int cy = cfg / 3, cx = cfg % 3;
            const int ylo = (cy == 2) ? 1 : 0, yhi = (cy == 0) ? 1 : 2;
            const int xlo = (cx == 2) ? 1 : 0, xhi = (cx == 0) ? 1 : 2;
            const float* wp = dw1 + ((size_t)i * 64 + o) * 9;
            float s = 0.f;
            for (int ky = ylo; ky <= yhi; ++ky)
                for (int kx = xlo; kx <= xhi; ++kx)
                    s += wp[ky * 3 + kx];
            Wcfg[gid] = s;
        } else if (gid < 81920) {
            const int k = gid - 73728;
            const float4* e = (const float4*)(emb + (size_t)k * 128);
            float s = 0.f;
            for (int t = 0; t < 32; ++t) {
                float4 v = e[t];
                s = fmaf(v.x, v.x, fmaf(v.y, v.y, fmaf(v.z, v.z, fmaf(v.w, v.w, s))));
            }
            en2[k] = s;
        }
        return;
    }

    // ---- conv blocks: 8 output rows each ----
    const int b = blk >> 3, rg = blk & 7;
    const int y0 = rg * 8;
    const float* pb = patch + (size_t)b * 12288;
    // padded layout: [ic][r:10][p:72], input x at p=x+3, row r holds y=y0+r-1
    for (int i = tid; i < 2160; i += 256) {
        const int c = i / 720, rem = i - c * 720;
        const int r = rem / 72, p = rem - r * 72;
        const int y = y0 + r - 1, x = p - 3;
        float v = 0.f;
        if (y >= 0 && y < 64 && x >= 0 && x < 64)
            v = pb[(c << 12) + (y << 6) + x];
        lds[i] = v;
    }
    __syncthreads();

    const int ch = tid & 63, q = tid >> 6;   // q: 2 rows each
    float w[3][3][3];
#pragma unroll
    for (int ic = 0; ic < 3; ++ic)
#pragma unroll
        for (int ky = 0; ky < 3; ++ky)
#pragma unroll
            for (int kx = 0; kx < 3; ++kx)
                w[ic][ky][kx] = w1[((ch * 3 + ic) * 3 + ky) * 3 + kx];
    const float bias = b1[ch];

    float T = 0, r0s = 0, r63s = 0, c0s = 0, c63s = 0;
    float h00 = 0, h063 = 0, h630 = 0, h6363 = 0;

#pragma unroll
    for (int sub = 0; sub < 2; ++sub) {
        const int yl = q * 2 + sub;
        const bool isr0  = (rg == 0) && (yl == 0);
        const bool isr63 = (rg == 7) && (yl == 7);
        float cr[3][3][2];   // sliding carry: p = xc*4+2, xc*4+3
#pragma unroll
        for (int ic = 0; ic < 3; ++ic)
#pragma unroll
            for (int ky = 0; ky < 3; ++ky) {
                const float2 t2 = *(const float2*)&lds[(ic * 10 + yl + ky) * 72 + 2];
                cr[ic][ky][0] = t2.x; cr[ic][ky][1] = t2.y;
            }
#pragma unroll 4
        for (int xc = 0; xc < 16; ++xc) {
            float a0 = bias, a1 = bias, a2 = bias, a3 = bias;
#pragma unroll
            for (int ic = 0; ic < 3; ++ic)
#pragma unroll
                for (int ky = 0; ky < 3; ++ky) {
                    const float4 nw = *(const float4*)&lds[(ic * 10 + yl + ky) * 72 + xc * 4 + 4];
                    const float w0 = w[ic][ky][0], w1v = w[ic][ky][1], w2v = w[ic][ky][2];
                    a0 = fmaf(w0, cr[ic][ky][0], fmaf(w1v, cr[ic][ky][1], fmaf(w2v, nw.x, a0)));
                    a1 = fmaf(w0, cr[ic][ky][1], fmaf(w1v, nw.x, fmaf(w2v, nw.y, a1)));
                    a2 = fmaf(w0, nw.x, fmaf(w1v, nw.y, fmaf(w2v, nw.z, a2)));
                    a3 = fmaf(w0, nw.y, fmaf(w1v, nw.z, fmaf(w2v, nw.w, a3)));
                    cr[ic][ky][0] = nw.z; cr[ic][ky][1] = nw.w;
                }
            a0 = fmaxf(a0, 0.f); a1 = fmaxf(a1, 0.f);
            a2 = fmaxf(a2, 0.f); a3 = fmaxf(a3, 0.f);
            const float rs = (a0 + a1) + (a2 + a3);
            T += rs;
            if (isr0)  { r0s += rs;  if (xc == 0) h00 = a0;  if (xc == 15) h063 = a3; }
            if (isr63) { r63s += rs; if (xc == 0) h630 = a0; if (xc == 15) h6363 = a3; }
            if (xc == 0)  c0s += a0;
            if (xc == 15) c63s += a3;
        }
    }
    __syncthreads();   // reuse lds for reduction
    {
        const float st[9] = {T, r0s, r63s, c0s, c63s, h00, h063, h630, h6363};
#pragma unroll
        for (int s = 0; s < 9; ++s) lds[(s * 4 + q) * 64 + ch] = st[s];
    }
    __syncthreads();
    if (tid < 64) {
        float* pp = pstat + (size_t)blk * 576;
#pragma unroll
        for (int s = 0; s < 9; ++s)
            pp[s * 64 + tid] = (lds[(s * 4 + 0) * 64 + tid] + lds[(s * 4 + 1) * 64 + tid])
                             + (lds[(s * 4 + 2) * 64 + tid] + lds[(s * 4 + 3) * 64 + tid]);
    }
}

// ------------------ K2: stats reduce + S + z-GEMM + ||z||^2 ------------------
__global__ __launch_bounds__(256) void k_zred(
    const float* __restrict__ pstat, const float* __restrict__ w2,
    const float* __restrict__ b2, float* __restrict__ z, float* __restrict__ zn2)
{
    __shared__ float fst[576];
    __shared__ __align__(16) float Ssh[576];
    __shared__ float zp[256];
    __shared__ float red2[128];
    const int b = blockIdx.x, tid = threadIdx.x;

    const float* pp = pstat + (size_t)b * 8 * 576;
    for (int i = tid; i < 576; i += 256) {
        float s = 0.f;
#pragma unroll
        for (int g = 0; g < 8; ++g) s += pp[g * 576 + i];
        fst[i] = s;
    }
    __syncthreads();

    if (tid < 64) {
        const float Tt   = fst[0 * 64 + tid], R0  = fst[1 * 64 + tid], R63 = fst[2 * 64 + tid];
        const float C0   = fst[3 * 64 + tid], C63 = fst[4 * 64 + tid];
        const float H00  = fst[5 * 64 + tid], H063 = fst[6 * 64 + tid];
        const float H630 = fst[7 * 64 + tid], H6363 = fst[8 * 64 + tid];
#pragma unroll
        for (int ky = 0; ky < 3; ++ky) {
            const float rex = (ky == 0) ? R63 : (ky == 2 ? R0 : 0.f);
#pragma unroll
            for (int kx = 0; kx < 3; ++kx) {
                const float cex = (kx == 0) ? C63 : (kx == 2 ? C0 : 0.f);
                float corner = 0.f;
                if (ky == 0 && kx == 0) corner = H6363;
                if (ky == 0 && kx == 2) corner = H630;
                if (ky == 2 && kx == 0) corner = H063;
                if (ky == 2 && kx == 2) corner = H00;
                Ssh[tid * 9 + ky * 3 + kx] = (Tt - rex - cex + corner) * (1.f / 4096.f);
            }
        }
    }
    __syncthreads();

    const int oc = tid & 127, h = tid >> 7;
    const float4* Wv = (const float4*)(w2 + (size_t)oc * 576 + h * 288);
    const float4* Sv = (const float4*)(Ssh + h * 288);
    float acc = 0.f;
    for (int t = 0; t < 72; ++t) {
        const float4 w4 = Wv[t], s4 = Sv[t];
        acc = fmaf(w4.x, s4.x, acc);
        acc = fmaf(w4.y, s4.y, acc);
        acc = fmaf(w4.z, s4.z, acc);
        acc = fmaf(w4.w, s4.w, acc);
    }
    zp[tid] = acc;
    __syncthreads();
    if (tid < 128) {
        const float zv = b2[tid] + zp[tid] + zp[tid + 128];
        z[(size_t)b * 128 + tid] = zv;
        red2[tid] = zv * zv;
    }
    __syncthreads();
    if (tid < 64) {
        float v = red2[tid] + red2[tid + 64];
        v += __shfl_xor(v, 32); v += __shfl_xor(v, 16); v += __shfl_xor(v, 8);
        v += __shfl_xor(v, 4);  v += __shfl_xor(v, 2);  v += __shfl_xor(v, 1);
        if (tid == 0) zn2[b] = v;
    }
}

// ------------------ K3: VQ partial argmin (32 bg x 16 kc) ------------------
__global__ __launch_bounds__(256) void k_vq(
    const float* __restrict__ z, const float* __restrict__ emb,
    const float* __restrict__ en2, float* __restrict__ pd2, int* __restrict__ pidx)
{
    __shared__ __align__(16) float zsh[1024];
    __shared__ float wd[8][4];
    __shared__ int   wi[8][4];
    const int tid = threadIdx.x;
    const int bg = blockIdx.x >> 4, kc = blockIdx.x & 15;
    const int b0 = bg * 8;
    for (int i = tid; i < 1024; i += 256) zsh[i] = z[(size_t)b0 * 128 + i];
    __syncthreads();

    const int k0 = kc * 512 + tid, k1 = k0 + 256;
    const float4* e0 = (const float4*)(emb + (size_t)k0 * 128);
    const float4* e1 = (const float4*)(emb + (size_t)k1 * 128);
    const float4* zv = (const float4*)zsh;

    float acc0[8], acc1[8];
#pragma unroll
    for (int bb = 0; bb < 8; ++bb) { acc0[bb] = 0.f; acc1[bb] = 0.f; }

    for (int t = 0; t < 32; ++t) {
        const float4 ea = e0[t], eb = e1[t];
#pragma unroll
        for (int bb = 0; bb < 8; ++bb) {
            const float4 zz = zv[bb * 32 + t];
            acc0[bb] = fmaf(zz.x, ea.x, fmaf(zz.y, ea.y, fmaf(zz.z, ea.z, fmaf(zz.w, ea.w, acc0[bb]))));
            acc1[bb] = fmaf(zz.x, eb.x, fmaf(zz.y, eb.y, fmaf(zz.z, eb.z, fmaf(zz.w, eb.w, acc1[bb]))));
        }
    }
    const float E0 = en2[k0], E1 = en2[k1];
    const int wv_ = tid >> 6, ln = tid & 63;
#pragma unroll
    for (int bb = 0; bb < 8; ++bb) {
        const float da = fmaf(-2.f, acc0[bb], E0);
        const float db = fmaf(-2.f, acc1[bb], E1);
        float d; int ix;
        if (da <= db) { d = da; ix = k0; } else { d = db; ix = k1; }
#pragma unroll
        for (int off = 32; off > 0; off >>= 1) {
            const float od = __shfl_xor(d, off);
            const int   oi = __shfl_xor(ix, off);
            if (od < d || (od == d && oi < ix)) { d = od; ix = oi; }
        }
        if (ln == 0) { wd[bb][wv_] = d; wi[bb][wv_] = ix; }
    }
    __syncthreads();
    if (tid < 8) {
        float d = wd[tid][0]; int ix = wi[tid][0];
#pragma unroll
        for (int wv2 = 1; wv2 < 4; ++wv2) {
            const float od = wd[tid][wv2]; const int oi = wi[tid][wv2];
            if (od < d || (od == d && oi < ix)) { d = od; ix = oi; }
        }
        pd2[(b0 + tid) * 16 + kc] = d;
        pidx[(b0 + tid) * 16 + kc] = ix;
    }
}

// ------------------ K4: argmin + losses + indices + full decoder + expand ------------------
__global__ __launch_bounds__(256) void k_decode(
    const float* __restrict__ emb, const float* __restrict__ zn2,
    const float* __restrict__ pd2, const int* __restrict__ pidx,
    const float* __restrict__ Wcfg, const float* __restrict__ db1,
    const float* __restrict__ dw2, const float* __restrict__ db2,
    const float* __restrict__ dw3, const float* __restrict__ db3,
    float* __restrict__ out)
{
    __shared__ __align__(16) float zsh[128];
    __shared__ float d1e[64][10];
    __shared__ float d2e[64][26];
    __shared__ float o3[3 * 49];
    __shared__ float dw3sh[1728];
    __shared__ float redl[256];
    __shared__ int bsel;

    const int b = blockIdx.x, tid = threadIdx.x;

    // ---- phase 0: final argmin, batch 'tid' per thread ----
    float dmin = pd2[tid * 16]; int bi = pidx[tid * 16];
    for (int j = 1; j < 16; ++j) {
        const float d = pd2[tid * 16 + j]; const int ix = pidx[tid * 16 + j];
        if (d < dmin || (d == dmin && ix < bi)) { dmin = d; bi = ix; }
    }
    if (tid == b) bsel = bi;
    redl[tid] = dmin + zn2[tid];
    __syncthreads();

    if (b == 0) out[3145730 + tid] = (float)bi;
    if (tid < 128) {
        redl[tid] += redl[tid + 128];
        zsh[tid] = emb[(size_t)bsel * 128 + tid];
    }
    for (int id = tid; id < 1728; id += 256) dw3sh[id] = dw3[id];
    if (tid < 64) { d1e[tid][9] = 0.f; d2e[tid][25] = 0.f; }
    __syncthreads();

    if (tid < 64) {
        float v = redl[tid] + redl[tid + 64];
        v += __shfl_xor(v, 32); v += __shfl_xor(v, 16); v += __shfl_xor(v, 8);
        v += __shfl_xor(v, 4);  v += __shfl_xor(v, 2);  v += __shfl_xor(v, 1);
        if (tid == 0 && b == 0) {
            const float L = v * (1.f / 32768.f);
            out[3145728] = L;
            out[3145729] = L;
        }
    }

    // ---- stage 1: d1e[o][cfg] = relu(db1 + Wcfg[cfg][o][:] . zq) ----
    for (int id = tid; id < 576; id += 256) {
        const int o = id / 9, cfg = id - o * 9;
        const float4* wv = (const float4*)(Wcfg + ((size_t)cfg * 64 + o) * 128);
        const float4* zv = (const float4*)zsh;
        float acc = db1[o];
        for (int t = 0; t < 32; ++t) {
            const float4 w4 = wv[t], z4 = zv[t];
            acc = fmaf(w4.x, z4.x, acc);
            acc = fmaf(w4.y, z4.y, acc);
            acc = fmaf(w4.z, z4.z, acc);
            acc = fmaf(w4.w, z4.w, acc);
        }
        d1e[o][cfg] = fmaxf(acc, 0.f);
    }
    __syncthreads();

    // ---- stage 2: 25 cfgs; thread = (o, i-quarter); shfl reduce ----
    {
        const int TY5[5][3] = {{-1,0,1},{0,1,1},{1,1,1},{1,1,2},{1,2,-1}};
        const int o = tid >> 2, isub = tid & 3;
        float acc[25];
#pragma unroll
        for (int cc = 0; cc < 25; ++cc) acc[cc] = 0.f;
        for (int ii = 0; ii < 16; ++ii) {
            const int i = isub + ii * 4;
            float d1v[10];
#pragma unroll
            for (int t = 0; t < 9; ++t) d1v[t] = d1e[i][t];
            d1v[9] = 0.f;
            const float* wp = dw2 + ((size_t)i * 64 + o) * 9;
            const float4u w03 = *(const float4u*)wp;
            const float4u w47 = *(const float4u*)(wp + 4);
            const float w8v = wp[8];
            const float w9[9] = {w03.x, w03.y, w03.z, w03.w, w47.x, w47.y, w47.z, w47.w, w8v};
#pragma unroll
            for (int cy = 0; cy < 5; ++cy) {
#pragma unroll
                for (int ky = 0; ky < 3; ++ky) {
                    const int ty = TY5[cy][ky];
                    if (ty < 0) continue;
#pragma unroll
                    for (int cx = 0; cx < 5; ++cx) {
#pragma unroll
                        for (int kx = 0; kx < 3; ++kx) {
                            const int tx = TY5[cx][kx];
                            if (tx < 0) continue;
                            acc[cy * 5 + cx] = fmaf(w9[(2 - ky) * 3 + (2 - kx)],
                                                    d1v[ty * 3 + tx], acc[cy * 5 + cx]);
                        }
                    }
                }
            }
        }
#pragma unroll
        for (int cc = 0; cc < 25; ++cc) {
            float v = acc[cc];
            v += __shfl_xor(v, 1);
            v += __shfl_xor(v, 2);
            if (isub == 0) d2e[o][cc] = fmaxf(v + db2[o], 0.f);
        }
    }
    __syncthreads();

    // ---- stage 3: 49 cfgs x 3 channels ----
    if (tid < 147) {
        const int TY7[7][3] = {{-1,0,1},{0,1,2},{1,2,2},{2,2,2},{2,2,3},{2,3,4},{3,4,-1}};
        const int c3 = tid / 49, cc = tid % 49, cy = cc / 7, cx = cc % 7;
        float acc = db3[c3];
        for (int i = 0; i < 64; ++i) {
            const float* wp = &dw3sh[(i * 3 + c3) * 9];
#pragma unroll
            for (int ky = 0; ky < 3; ++ky) {
                const int ty = TY7[cy][ky];
#pragma unroll
                for (int kx = 0; kx < 3; ++kx) {
                    const int tx = TY7[cx][kx];
                    const int t = (ty < 0 || tx < 0) ? 25 : ty * 5 + tx;
                    acc = fmaf(wp[(2 - ky) * 3 + (2 - kx)], d2e[i][t], acc);
                }
            }
        }
        o3[c3 * 49 + cc] = tanhf(acc);
    }
    __syncthreads();

    // ---- expand + float4 write ----
    float4* ob = (float4*)(out + (size_t)b * 12288);
    for (int id = tid; id < 3072; id += 256) {
        const int base = id * 4;
        const int c = base >> 12, rem = base & 4095, y = rem >> 6, x0 = rem & 63;
        const int ry = (y <= 3) ? y : (y >= 60 ? y - 57 : 3);
        const float* row = &o3[c * 49 + ry * 7];
        float4 v;
        int x;
        x = x0 + 0; v.x = row[(x <= 3) ? x : (x >= 60 ? x - 57 : 3)];
        x = x0 + 1; v.y = row[(x <= 3) ? x : (x >= 60 ? x - 57 : 3)];
        x = x0 + 2; v.z = row[(x <= 3) ? x : (x >= 60 ? x - 57 : 3)];
        x = x0 + 3; v.w = row[(x <= 3) ? x : (x >= 60 ? x - 57 : 3)];
        ob[id] = v;
    }
}

// ---------------------------------------------------------------------------
extern "C" void kernel_launch(void* const* d_in, const int* in_sizes, int n_in,
                              void* d_out, int out_size, void* d_ws, size_t ws_size,
                              hipStream_t stream)
{
    const float* patch  = (const float*)d_in[0];
    const float* enc_w1 = (const float*)d_in[1];
    const float* enc_b1 = (const float*)d_in[2];
    const float* enc_w2 = (const float*)d_in[3];
    const float* enc_b2 = (const float*)d_in[4];
    const float* emb    = (const float*)d_in[5];
    const float* dec_w1 = (const float*)d_in[6];
    const float* dec_b1 = (const float*)d_in[7];
    const float* dec_w2 = (const float*)d_in[8];
    const float* dec_b2 = (const float*)d_in[9];
    const float* dec_w3 = (const float*)d_in[10];
    const float* dec_b3 = (const float*)d_in[11];

    float* out = (float*)d_out;
    float* ws  = (float*)d_ws;

    float* pstat = ws;                     // 2048*576 = 1179648
    float* z     = ws + 1179648;           // 32768
    float* zn2   = ws + 1212416;           // 256
    float* pd2   = ws + 1212672;           // 4096
    int*   pidx  = (int*)(ws + 1216768);   // 4096
    float* Wcfg  = ws + 1220864;           // 73728
    float* en2   = ws + 1294592;           // 8192

    k_conv1_pre<<<dim3(2368), dim3(256), 0, stream>>>(patch, enc_w1, enc_b1, dec_w1,
                                                      emb, pstat, Wcfg, en2);
    k_zred<<<dim3(256), dim3(256), 0, stream>>>(pstat, enc_w2, enc_b2, z, zn2);
    k_vq<<<dim3(512), dim3(256), 0, stream>>>(z, emb, en2, pd2, pidx);
    k_decode<<<dim3(256), dim3(256), 0, stream>>>(emb, zn2, pd2, pidx, Wcfg, dec_b1,
                                                  dec_w2, dec_b2, dec_w3, dec_b3, out);
}